// Round 4
// baseline (164.515 us; speedup 1.0000x reference)
//
#include <hip/hip_runtime.h>

// Problem constants
#define BB 8
#define CIN 256
#define NE 64
#define HH 128
#define WW 128
#define TOPK 8

#define TSX 16               // tile 16 wide
#define TSY 8                // x 8 tall -> 128 px/block, 1024 blocks
#define HLX 18
#define HLY 10
#define NSP (HLY*HLX)        // 180 spatial positions incl halo
#define CC   32              // channels per K-chunk
#define NCH  (CIN/CC)        // 8 chunks
#define XROW 128             // x LDS row bytes: [32ch hi bf16 | 32ch lo], XOR-swizzled
#define ROWB 144             // w LDS row bytes: [32ch hi | 32ch lo | 16B pad]

// d_out layout (float32 view): weights | indices | counts | new_bias
#define W_OFF  0
#define I_OFF  (BB*TOPK*HH*WW)
#define C_OFF  (2*BB*TOPK*HH*WW)
#define NB_OFF (C_OFF + NE)

#define WROWS (NCH*9*NE)            // 4608 rows in the split-weight image
#define WSPLIT_BYTES (WROWS*ROWB)   // 663552 B

typedef __attribute__((ext_vector_type(8))) __bf16 bf16x8;   // 4 VGPR MFMA operand
typedef __attribute__((ext_vector_type(4))) float f32x4;     // 4 VGPR accumulator

// ---- prep: split weights to bf16 hi/lo in the exact LDS image layout ----
// row index: ((chunk*3 + ky)*3 + kx)*64 + e ; row = hi ch0..31 (64B) | lo ch0..31 (64B) | pad
__global__ void split_w(const float* __restrict__ wg, char* __restrict__ wsplit) {
    int i = blockIdx.x * 256 + threadIdx.x;
    if (i >= WROWS * 16) return;
    int cp  = i & 15;                 // channel pair within chunk
    int row = i >> 4;
    int c   = row / (9 * NE);
    int r2  = row % (9 * NE);
    int ky  = r2 / (3 * NE);
    int r3  = r2 % (3 * NE);
    int kx  = r3 / NE;
    int e   = r3 % NE;
    int ch  = c * CC + cp * 2;
    const float* src = wg + ((size_t)e * CIN + ch) * 9 + ky * 3 + kx;
    float f0 = src[0], f1 = src[9];
    unsigned u0 = __float_as_uint(f0), u1 = __float_as_uint(f1);
    float r0 = f0 - __uint_as_float(u0 & 0xffff0000u);
    float r1 = f1 - __uint_as_float(u1 & 0xffff0000u);
    char* base = wsplit + (size_t)row * ROWB;
    *(unsigned*)(base + cp * 4)      = (u0 >> 16) | (u1 & 0xffff0000u);
    *(unsigned*)(base + 64 + cp * 4) = (__float_as_uint(r0) >> 16) | (__float_as_uint(r1) & 0xffff0000u);
}

union Smem {
    struct { char xs[NSP * XROW]; char wb[NE * ROWB]; } st;  // 23040 + 9216 = 32256 B
    float scores[128][65];                                   // 33280 B (epilogue)
};

__global__ __launch_bounds__(128, 2) void conv_mfma_kernel(
    const float* __restrict__ x, const char* __restrict__ wsplit,
    const float* __restrict__ bias, float* __restrict__ out,
    int* __restrict__ gcount)
{
    __shared__ __align__(16) Smem sm;
    __shared__ int hist[NE];
    __shared__ float sbias[NE];

    const int tid  = threadIdx.x;        // 128 threads = 2 waves
    const int lane = tid & 63;
    const int wv   = tid >> 6;           // wave 0..1 -> pixel rows wv*4..wv*4+3
    const int b    = blockIdx.z;
    const int by0  = blockIdx.y * TSY, bx0 = blockIdx.x * TSX;
    const float* xb = x + (size_t)b * CIN * HH * WW;

    if (tid < NE) { hist[tid] = 0; sbias[tid] = bias[tid]; }

    const int er = lane & 15;            // A: pixel col / B: expert-in-tile / C: col
    const int kg = lane >> 4;            // k-group 0..3 (8 ch each)

    f32x4 acc[4][4];                     // [Mtile][Ntile]
    #pragma unroll
    for (int m = 0; m < 4; ++m)
        #pragma unroll
        for (int n = 0; n < 4; ++n) acc[m][n] = (f32x4){0.f, 0.f, 0.f, 0.f};

    for (int c = 0; c < NCH; ++c) {
        __syncthreads();                 // previous chunk's x readers done
        // ---- stage x chunk: 180 spatial x 32 ch, split hi/lo, XOR-swizzled rows ----
        #pragma unroll
        for (int cq = 0; cq < 8; ++cq) {
            for (int s = tid; s < NSP; s += 128) {
                int row = s / HLX, col = s - row * HLX;
                int gy = by0 - 1 + row, gx = bx0 - 1 + col;
                bool ok = ((unsigned)gy < (unsigned)HH) && ((unsigned)gx < (unsigned)WW);
                const float* p = xb + (size_t)(c * CC + cq * 4) * (HH * WW) + gy * WW + gx;
                float f0 = ok ? p[0]           : 0.f;
                float f1 = ok ? p[HH * WW]     : 0.f;
                float f2 = ok ? p[2 * HH * WW] : 0.f;
                float f3 = ok ? p[3 * HH * WW] : 0.f;
                unsigned u0 = __float_as_uint(f0), u1 = __float_as_uint(f1);
                unsigned u2 = __float_as_uint(f2), u3 = __float_as_uint(f3);
                float r0 = f0 - __uint_as_float(u0 & 0xffff0000u);
                float r1 = f1 - __uint_as_float(u1 & 0xffff0000u);
                float r2 = f2 - __uint_as_float(u2 & 0xffff0000u);
                float r3 = f3 - __uint_as_float(u3 & 0xffff0000u);
                uint2 hi2, lo2;
                hi2.x = (u0 >> 16) | (u1 & 0xffff0000u);
                hi2.y = (u2 >> 16) | (u3 & 0xffff0000u);
                lo2.x = (__float_as_uint(r0) >> 16) | (__float_as_uint(r1) & 0xffff0000u);
                lo2.y = (__float_as_uint(r2) >> 16) | (__float_as_uint(r3) & 0xffff0000u);
                int off = (s * XROW + cq * 8) ^ ((s & 7) << 4);
                *(uint2*)(&sm.st.xs[off])       = hi2;
                *(uint2*)(&sm.st.xs[off ^ 64])  = lo2;
            }
        }
        __syncthreads();                 // x staged

        #pragma unroll
        for (int kx = 0; kx < 3; ++kx) {
            // ---- A-fragment register cache: 6 rows (shared across ky) ----
            bf16x8 Ah[6], Al[6];
            #pragma unroll
            for (int rr = 0; rr < 6; ++rr) {
                int s = (wv * 4 + rr) * HLX + er + kx;
                int off = (s * XROW + kg * 16) ^ ((s & 7) << 4);
                Ah[rr] = *(const bf16x8*)(sm.st.xs + off);
                Al[rr] = *(const bf16x8*)(sm.st.xs + (off ^ 64));
            }
            #pragma unroll
            for (int ky = 0; ky < 3; ++ky) {
                __syncthreads();         // previous w readers done
                // ---- stage w[c][ky][kx]: 9216 B linear copy via global_load_lds ----
                {
                    const char* wsrc = wsplit + (size_t)((c * 3 + ky) * 3 + kx) * (NE * ROWB);
                    for (int i = tid; i < (NE * ROWB) / 16; i += 128)
                        __builtin_amdgcn_global_load_lds(
                            (const __attribute__((address_space(1))) void*)(wsrc + i * 16),
                            (__attribute__((address_space(3))) void*)(sm.st.wb + i * 16),
                            16, 0, 0);
                }
                __syncthreads();         // drains vmcnt -> w staged

                bf16x8 Bh[4], Bl[4];
                #pragma unroll
                for (int n = 0; n < 4; ++n) {
                    const char* wr = sm.st.wb + (n * 16 + er) * ROWB + kg * 16;
                    Bh[n] = *(const bf16x8*)wr;
                    Bl[n] = *(const bf16x8*)(wr + 64);
                }
                // 3 passes (hh, lh, hl): no back-to-back same-acc MFMA chains
                #pragma unroll
                for (int n = 0; n < 4; ++n)
                    #pragma unroll
                    for (int m = 0; m < 4; ++m)
                        acc[m][n] = __builtin_amdgcn_mfma_f32_16x16x32_bf16(Ah[m + ky], Bh[n], acc[m][n], 0, 0, 0);
                #pragma unroll
                for (int n = 0; n < 4; ++n)
                    #pragma unroll
                    for (int m = 0; m < 4; ++m)
                        acc[m][n] = __builtin_amdgcn_mfma_f32_16x16x32_bf16(Al[m + ky], Bh[n], acc[m][n], 0, 0, 0);
                #pragma unroll
                for (int n = 0; n < 4; ++n)
                    #pragma unroll
                    for (int m = 0; m < 4; ++m)
                        acc[m][n] = __builtin_amdgcn_mfma_f32_16x16x32_bf16(Ah[m + ky], Bl[n], acc[m][n], 0, 0, 0);
            }
        }
    }

    // ---- epilogue: sigmoid+bias -> LDS scores [pixel][expert] ----
    __syncthreads();                     // staging buffers dead; reuse as scores
    #pragma unroll
    for (int m = 0; m < 4; ++m) {
        int pixbase = (wv * 4 + m) * 16 + kg * 4;   // C row = (lane>>4)*4 + reg
        #pragma unroll
        for (int n = 0; n < 4; ++n) {
            int e = n * 16 + er;                    // C col = lane&15
            float bval = sbias[e];
            #pragma unroll
            for (int r = 0; r < 4; ++r)
                sm.scores[pixbase + r][e] = 1.f / (1.f + __expf(-acc[m][n][r])) + bval;
        }
    }
    __syncthreads();

    // ---- per-pixel top-8 (strict >, lowest index wins: matches lax.top_k) ----
    {
        float* row = sm.scores[tid];     // 128 threads, 1 pixel each
        float selv[TOPK]; int seli[TOPK];
        #pragma unroll
        for (int j = 0; j < TOPK; ++j) {
            float bv = -1e38f; int bidx = 0;
            #pragma unroll
            for (int e = 0; e < NE; ++e) {
                float v = row[e];
                bool gt = v > bv;
                bv   = gt ? v : bv;
                bidx = gt ? e : bidx;
            }
            selv[j] = bv - sbias[bidx];  // recover UNbiased score
            seli[j] = bidx;
            row[bidx] = -3e38f;          // mask winner
        }
        float mx = selv[0];
        #pragma unroll
        for (int j = 1; j < TOPK; ++j) mx = fmaxf(mx, selv[j]);
        float ex[TOPK]; float ssum = 0.f;
        #pragma unroll
        for (int j = 0; j < TOPK; ++j) { ex[j] = __expf(selv[j] - mx); ssum += ex[j]; }
        const float inv = 1.f / ssum;

        const int pyg = by0 + (tid >> 4), pxg = bx0 + (tid & 15);
        #pragma unroll
        for (int j = 0; j < TOPK; ++j) {
            size_t o = ((size_t)(b * TOPK + j) * HH + pyg) * WW + pxg;
            out[W_OFF + o] = ex[j] * inv;
            out[I_OFF + o] = (float)seli[j];
            atomicAdd(&hist[seli[j]], 1);
        }
    }
    __syncthreads();
    if (tid < NE) atomicAdd(&gcount[tid], hist[tid]);
}

__global__ void finalize_kernel(const float* __restrict__ bias,
                                const float* __restrict__ history,
                                const int* __restrict__ gcount,
                                float* __restrict__ out)
{
    const int e = threadIdx.x;   // 64 threads = 1 wave
    float c = history[e] + (float)gcount[e];
    if (__all(c > 1e8f)) c = fmodf(c, 1e8f);
    float sum = c;
    #pragma unroll
    for (int off = 32; off > 0; off >>= 1) sum += __shfl_down(sum, off);
    float mean = __shfl(sum, 0) * (1.f / 64.f);
    float d = mean - c;
    float sg = (d > 0.f) ? 1.f : ((d < 0.f) ? -1.f : 0.f);
    out[C_OFF + e]  = c;
    out[NB_OFF + e] = bias[e] + 0.001f * sg;
}

extern "C" void kernel_launch(void* const* d_in, const int* in_sizes, int n_in,
                              void* d_out, int out_size, void* d_ws, size_t ws_size,
                              hipStream_t stream) {
    const float* x       = (const float*)d_in[0];
    const float* wg      = (const float*)d_in[1];
    const float* bias    = (const float*)d_in[2];
    const float* history = (const float*)d_in[3];
    float* out = (float*)d_out;

    char* wsplit = (char*)d_ws;
    int* gcount  = (int*)((char*)d_ws + WSPLIT_BYTES);

    hipMemsetAsync(gcount, 0, NE * sizeof(int), stream);
    split_w<<<(WROWS * 16 + 255) / 256, 256, 0, stream>>>(wg, wsplit);
    conv_mfma_kernel<<<dim3(WW / TSX, HH / TSY, BB), 128, 0, stream>>>(x, wsplit, bias, out, gcount);
    finalize_kernel<<<1, 64, 0, stream>>>(bias, history, gcount, out);
}

// Round 5
// 99.338 us; speedup vs baseline: 1.6561x; 1.6561x over previous
//
#include <hip/hip_runtime.h>

// Problem constants
#define BB 8
#define CIN 256
#define NE 64
#define HH 128
#define WW 128
#define HW (HH*WW)
#define TOPK 8

#define TS   16              // 16x16 pixel tile, 512 blocks, 2 blocks/CU
#define HLX  18
#define NSP  (HLX*HLX)       // 324 spatial positions incl halo
#define CC   32              // channels per K-chunk
#define NCH  (CIN/CC)        // 8 chunks
#define XROW 64              // x LDS row bytes: 32 ch fp16, XOR-swizzled granules
#define XBUF (NSP*XROW)      // 20736 B per x buffer
#define WCH  (9*NE*XROW)     // 36864 B per w chunk (9 taps x 64 e x 32 ch fp16)

// d_out layout (float32 view): weights | indices | counts | new_bias
#define W_OFF  0
#define I_OFF  (BB*TOPK*HH*WW)
#define C_OFF  (2*BB*TOPK*HH*WW)
#define NB_OFF (C_OFF + NE)

#define WIMG_BYTES (NCH*WCH)   // 294912

using f16x8 = __attribute__((ext_vector_type(8))) _Float16;
using f16x2 = __attribute__((ext_vector_type(2))) _Float16;
using f32x4 = __attribute__((ext_vector_type(4))) float;

#define GLDS16(gsrc, ldst) __builtin_amdgcn_global_load_lds( \
    (const __attribute__((address_space(1))) void*)(gsrc),   \
    (__attribute__((address_space(3))) void*)(ldst), 16, 0, 0)

// ---- prep: w fp32 [e][cin][3][3] -> fp16 pre-swizzled image ----
// image[c][tap*64+e] rows of 64 B (ch0..31 fp16); 16B granule g stored at g^(e&3)
__global__ void prep_w(const float* __restrict__ wg, char* __restrict__ wimg) {
    int i = blockIdx.x * 256 + threadIdx.x;      // over 73728 ch-pairs
    if (i >= NCH * 9 * NE * 16) return;
    int cp = i & 15; int t = i >> 4;
    int e  = t & 63; int t2 = t >> 6;
    int tap = t2 % 9; int c = t2 / 9;
    int ch  = c * CC + cp * 2;
    const float* src = wg + ((size_t)e * CIN + ch) * 9 + tap;
    unsigned u = (unsigned)__builtin_bit_cast(unsigned short, (_Float16)src[0]) |
                 ((unsigned)__builtin_bit_cast(unsigned short, (_Float16)src[9]) << 16);
    int row = tap * 64 + e;
    *(unsigned*)(wimg + (size_t)c * WCH + row * 64 +
                 (((cp >> 2) ^ (e & 3)) << 4) + (cp & 3) * 4) = u;
}

union Smem {
    struct { char xs[2][XBUF]; char wb[WCH]; } st;   // 78336 B
    float scores[256][65];                           // 66560 B (epilogue)
};

__global__ __launch_bounds__(256, 2) void conv_mfma_kernel(
    const float* __restrict__ x, const char* __restrict__ wimg,
    const float* __restrict__ bias, float* __restrict__ out,
    int* __restrict__ gcount)
{
    __shared__ __align__(16) Smem sm;
    __shared__ int hist[NE];
    __shared__ float sbias[NE];

    const int tid  = threadIdx.x;        // 256 threads = 4 waves
    const int lane = tid & 63;
    const int wv   = tid >> 6;
    const int b    = blockIdx.z;
    const int by0  = blockIdx.y * TS, bx0 = blockIdx.x * TS;
    const float* xb = x + (size_t)b * CIN * HW;

    if (tid < NE) { hist[tid] = 0; sbias[tid] = bias[tid]; }

    const int er = lane & 15;            // A: pixel row-of-16 / B: expert-in-tile
    const int kg = lane >> 4;            // k-group (8 ch)

    f32x4 acc[4][4];
    #pragma unroll
    for (int m = 0; m < 4; ++m)
        #pragma unroll
        for (int n = 0; n < 4; ++n) acc[m][n] = (f32x4){0.f, 0.f, 0.f, 0.f};

    float xr[6][8];                      // in-flight x registers (T14 issue-early)

    // ---- x load issue for chunk cc: groups g=(s,cp): 8 ch each, coalesced in s ----
#define X_ISSUE(cc)                                                         \
    _Pragma("unroll")                                                       \
    for (int k = 0; k < 6; ++k) {                                           \
        int g = tid + k * 256;                                              \
        if (g < 1296) {                                                     \
            int s = g % NSP, cp = g / NSP;                                  \
            int gy = by0 - 1 + s / HLX, gx = bx0 - 1 + s % HLX;             \
            bool ok = ((unsigned)gy < (unsigned)HH) && ((unsigned)gx < (unsigned)WW); \
            const float* p = xb + (size_t)((cc) * CC + cp * 8) * HW + gy * WW + gx;   \
            _Pragma("unroll")                                               \
            for (int q = 0; q < 8; ++q) xr[k][q] = ok ? p[q * HW] : 0.f;    \
        }                                                                   \
    }

    // ---- convert + swizzled LDS write into buffer xd ----
#define X_WRITE(xd)                                                         \
    _Pragma("unroll")                                                       \
    for (int k = 0; k < 6; ++k) {                                           \
        int g = tid + k * 256;                                              \
        if (g < 1296) {                                                     \
            int s = g % NSP, cp = g / NSP;                                  \
            uint4 u4;                                                       \
            u4.x = __builtin_bit_cast(unsigned, __builtin_amdgcn_cvt_pkrtz(xr[k][0], xr[k][1])); \
            u4.y = __builtin_bit_cast(unsigned, __builtin_amdgcn_cvt_pkrtz(xr[k][2], xr[k][3])); \
            u4.z = __builtin_bit_cast(unsigned, __builtin_amdgcn_cvt_pkrtz(xr[k][4], xr[k][5])); \
            u4.w = __builtin_bit_cast(unsigned, __builtin_amdgcn_cvt_pkrtz(xr[k][6], xr[k][7])); \
            *(uint4*)((xd) + ((s * 64 + cp * 16) ^ ((s & 3) << 4))) = u4;   \
        }                                                                   \
    }

#define W_STAGE(cc)                                                         \
    {                                                                       \
        const char* wsrc = wimg + (size_t)(cc) * WCH;                       \
        for (int i = tid; i < WCH / 16; i += 256)                           \
            GLDS16(wsrc + i * 16, sm.st.wb + i * 16);                       \
    }

    // ---- prologue: stage chunk 0 ----
    X_ISSUE(0)
    W_STAGE(0)
    X_WRITE(sm.st.xs[0])
    __syncthreads();

    #pragma unroll 1
    for (int c = 0; c < NCH; ++c) {
        const char* xcur = sm.st.xs[c & 1];
        if (c < NCH - 1) { X_ISSUE(c + 1) }          // HBM latency hides under compute

        #pragma unroll
        for (int kx = 0; kx < 3; ++kx) {
            f16x8 A[6];
            #pragma unroll
            for (int rr = 0; rr < 6; ++rr) {
                int s = (wv * 4 + rr) * HLX + er + kx;
                A[rr] = *(const f16x8*)(xcur + ((s * 64 + kg * 16) ^ ((s & 3) << 4)));
            }
            #pragma unroll
            for (int ky = 0; ky < 3; ++ky) {
                const int tap = ky * 3 + kx;
                f16x8 Bf[4];
                #pragma unroll
                for (int n = 0; n < 4; ++n) {
                    int row = tap * 64 + n * 16 + er;
                    Bf[n] = *(const f16x8*)(sm.st.wb + ((row * 64 + kg * 16) ^ ((row & 3) << 4)));
                }
                #pragma unroll
                for (int n = 0; n < 4; ++n)
                    #pragma unroll
                    for (int m = 0; m < 4; ++m)
                        acc[m][n] = __builtin_amdgcn_mfma_f32_16x16x32_f16(A[m + ky], Bf[n], acc[m][n], 0, 0, 0);
            }
        }
        __syncthreads();                 // compute done: wb and xs[nxt] free
        if (c < NCH - 1) {
            W_STAGE(c + 1)               // async L2->LDS
            X_WRITE(sm.st.xs[(c + 1) & 1])
        }
        __syncthreads();                 // drains glds + ds_writes
    }

    // ---- epilogue: sigmoid+bias -> LDS scores [pixel][expert] ----
    #pragma unroll
    for (int m = 0; m < 4; ++m) {
        int pixbase = (wv * 4 + m) * 16 + kg * 4;    // C: row=(lane>>4)*4+reg, col=lane&15
        #pragma unroll
        for (int n = 0; n < 4; ++n) {
            int e = n * 16 + er;
            float bval = sbias[e];
            #pragma unroll
            for (int r = 0; r < 4; ++r)
                sm.scores[pixbase + r][e] =
                    __builtin_amdgcn_rcpf(1.f + __expf(-acc[m][n][r])) + bval;
        }
    }
    __syncthreads();

    // ---- per-pixel top-8 in registers (strict >, lowest index wins) ----
    {
        float v[64];
        #pragma unroll
        for (int e = 0; e < 64; ++e) v[e] = sm.scores[tid][e];   // b32: 2-way, free

        float selv[TOPK]; int seli[TOPK];
        #pragma unroll
        for (int j = 0; j < TOPK; ++j) {
            float bv = -1e38f; int bidx = 0;
            #pragma unroll
            for (int e = 0; e < 64; ++e) {
                bool gt = v[e] > bv;
                bv   = gt ? v[e] : bv;
                bidx = gt ? e : bidx;
            }
            selv[j] = bv - sbias[bidx];  // recover UNbiased score
            seli[j] = bidx;
            #pragma unroll
            for (int e = 0; e < 64; ++e) v[e] = (e == bidx) ? -3e38f : v[e];
        }
        float mx = selv[0];
        #pragma unroll
        for (int j = 1; j < TOPK; ++j) mx = fmaxf(mx, selv[j]);
        float ex[TOPK]; float ssum = 0.f;
        #pragma unroll
        for (int j = 0; j < TOPK; ++j) { ex[j] = __expf(selv[j] - mx); ssum += ex[j]; }
        const float inv = 1.f / ssum;

        const int pyg = by0 + (tid >> 4), pxg = bx0 + (tid & 15);
        #pragma unroll
        for (int j = 0; j < TOPK; ++j) {
            size_t o = ((size_t)(b * TOPK + j) * HH + pyg) * WW + pxg;
            out[W_OFF + o] = ex[j] * inv;
            out[I_OFF + o] = (float)seli[j];
            atomicAdd(&hist[seli[j]], 1);
        }
    }
    __syncthreads();
    if (tid < NE) atomicAdd(&gcount[tid], hist[tid]);
}

__global__ void finalize_kernel(const float* __restrict__ bias,
                                const float* __restrict__ history,
                                const int* __restrict__ gcount,
                                float* __restrict__ out)
{
    const int e = threadIdx.x;   // 64 threads = 1 wave
    float c = history[e] + (float)gcount[e];
    if (__all(c > 1e8f)) c = fmodf(c, 1e8f);
    float sum = c;
    #pragma unroll
    for (int off = 32; off > 0; off >>= 1) sum += __shfl_down(sum, off);
    float mean = __shfl(sum, 0) * (1.f / 64.f);
    float d = mean - c;
    float sg = (d > 0.f) ? 1.f : ((d < 0.f) ? -1.f : 0.f);
    out[C_OFF + e]  = c;
    out[NB_OFF + e] = bias[e] + 0.001f * sg;
}

extern "C" void kernel_launch(void* const* d_in, const int* in_sizes, int n_in,
                              void* d_out, int out_size, void* d_ws, size_t ws_size,
                              hipStream_t stream) {
    const float* x       = (const float*)d_in[0];
    const float* wg      = (const float*)d_in[1];
    const float* bias    = (const float*)d_in[2];
    const float* history = (const float*)d_in[3];
    float* out = (float*)d_out;

    char* wimg  = (char*)d_ws;
    int* gcount = (int*)((char*)d_ws + WIMG_BYTES);

    hipMemsetAsync(gcount, 0, NE * sizeof(int), stream);
    prep_w<<<(NCH * 9 * NE * 16 + 255) / 256, 256, 0, stream>>>(wg, wimg);
    conv_mfma_kernel<<<dim3(WW / TS, HH / TS, BB), 256, 0, stream>>>(x, wimg, bias, out, gcount);
    finalize_kernel<<<1, 64, 0, stream>>>(bias, history, gcount, out);
}

// Round 6
// 93.497 us; speedup vs baseline: 1.7596x; 1.0625x over previous
//
#include <hip/hip_runtime.h>

// Problem constants
#define BB 8
#define CIN 256
#define NE 64
#define HH 128
#define WW 128
#define HW (HH*WW)
#define TOPK 8

#define TS   16              // 16x16 pixel tile, 512 blocks, 2 blocks/CU
#define HLX  18
#define NSP  (HLX*HLX)       // 324 spatial positions incl halo
#define NG   (NSP*4)         // 1296 (s, cp) staging groups, 8 ch each
#define CC   32              // channels per K-chunk
#define NCH  (CIN/CC)        // 8 chunks
#define XROW 64              // x LDS row bytes: 32 ch fp16, XOR-swizzled granules
#define XBUF (NSP*XROW)      // 20736 B per x buffer
#define WCH  (9*NE*XROW)     // 36864 B per w chunk

// d_out layout (float32 view): weights | indices | counts | new_bias
#define W_OFF  0
#define I_OFF  (BB*TOPK*HH*WW)
#define C_OFF  (2*BB*TOPK*HH*WW)
#define NB_OFF (C_OFF + NE)

#define WIMG_BYTES (NCH*WCH)   // 294912

using f16x8 = __attribute__((ext_vector_type(8))) _Float16;
using f32x4 = __attribute__((ext_vector_type(4))) float;

#define GLDS16(gsrc, ldst) __builtin_amdgcn_global_load_lds( \
    (const __attribute__((address_space(1))) void*)(gsrc),   \
    (__attribute__((address_space(3))) void*)(ldst), 16, 0, 0)

// ---- prep: w fp32 [e][cin][3][3] -> fp16 pre-swizzled image ----
__global__ void prep_w(const float* __restrict__ wg, char* __restrict__ wimg) {
    int i = blockIdx.x * 256 + threadIdx.x;
    if (i >= NCH * 9 * NE * 16) return;
    int cp = i & 15; int t = i >> 4;
    int e  = t & 63; int t2 = t >> 6;
    int tap = t2 % 9; int c = t2 / 9;
    int ch  = c * CC + cp * 2;
    const float* src = wg + ((size_t)e * CIN + ch) * 9 + tap;
    unsigned u = (unsigned)__builtin_bit_cast(unsigned short, (_Float16)src[0]) |
                 ((unsigned)__builtin_bit_cast(unsigned short, (_Float16)src[9]) << 16);
    int row = tap * 64 + e;
    *(unsigned*)(wimg + (size_t)c * WCH + row * 64 +
                 (((cp >> 2) ^ (e & 3)) << 4) + (cp & 3) * 4) = u;
}

union Smem {
    struct { char xs[2][XBUF]; char wb[WCH]; } st;   // 78336 B
    float scores[256][65];                           // 66560 B (epilogue)
};

__global__ __launch_bounds__(256, 2) void conv_mfma_kernel(
    const float* __restrict__ x, const char* __restrict__ wimg,
    const float* __restrict__ bias, float* __restrict__ out,
    int* __restrict__ gcount)
{
    __shared__ __align__(16) Smem sm;
    __shared__ int hist[NE];
    __shared__ float sbias[NE];

    const int tid  = threadIdx.x;        // 256 threads = 4 waves
    const int lane = tid & 63;
    const int wv   = tid >> 6;
    const int b    = blockIdx.z;
    const int by0  = blockIdx.y * TS, bx0 = blockIdx.x * TS;
    const float* xb = x + (size_t)b * CIN * HW;

    if (tid < NE) { hist[tid] = 0; sbias[tid] = bias[tid]; }

    const int er = lane & 15;
    const int kg = lane >> 4;

    // ---- hoisted staging addresses (loop-invariant) ----
    int srcIdx[6]; int ldsOff[6]; bool okm[6]; bool act[6];
    #pragma unroll
    for (int k = 0; k < 6; ++k) {
        int g  = tid + k * 256;
        int s  = g % NSP, cp = g / NSP;
        int gy = by0 - 1 + s / HLX, gx = bx0 - 1 + s % HLX;
        act[k] = (g < NG);
        okm[k] = act[k] && ((unsigned)gy < (unsigned)HH) && ((unsigned)gx < (unsigned)WW);
        srcIdx[k] = okm[k] ? (cp * 8 * HW + gy * WW + gx) : 0;
        ldsOff[k] = (s * 64 + cp * 16) ^ ((s & 3) << 4);
    }

    f32x4 acc[4][4];
    #pragma unroll
    for (int m = 0; m < 4; ++m)
        #pragma unroll
        for (int n = 0; n < 4; ++n) acc[m][n] = (f32x4){0.f, 0.f, 0.f, 0.f};

    float xr1[3][8], xr2[3][8];          // two in-flight halves

#define X_ISSUE_H(cc, K0, XR)                                               \
    _Pragma("unroll")                                                       \
    for (int k = 0; k < 3; ++k) {                                           \
        if (act[K0 + k]) {                                                  \
            const float* p = xb + (size_t)(cc) * (CC * HW) + srcIdx[K0 + k];\
            _Pragma("unroll")                                               \
            for (int q = 0; q < 8; ++q)                                     \
                XR[k][q] = okm[K0 + k] ? p[q * HW] : 0.f;                   \
        }                                                                   \
    }

#define X_WRITE_H(xd, K0, XR)                                               \
    _Pragma("unroll")                                                       \
    for (int k = 0; k < 3; ++k) {                                           \
        if (act[K0 + k]) {                                                  \
            uint4 u4;                                                       \
            u4.x = __builtin_bit_cast(unsigned, __builtin_amdgcn_cvt_pkrtz(XR[k][0], XR[k][1])); \
            u4.y = __builtin_bit_cast(unsigned, __builtin_amdgcn_cvt_pkrtz(XR[k][2], XR[k][3])); \
            u4.z = __builtin_bit_cast(unsigned, __builtin_amdgcn_cvt_pkrtz(XR[k][4], XR[k][5])); \
            u4.w = __builtin_bit_cast(unsigned, __builtin_amdgcn_cvt_pkrtz(XR[k][6], XR[k][7])); \
            *(uint4*)((xd) + ldsOff[K0 + k]) = u4;                          \
        }                                                                   \
    }

#define W_STAGE(cc)                                                         \
    {                                                                       \
        const char* wsrc = wimg + (size_t)(cc) * WCH;                       \
        for (int i = tid; i < WCH / 16; i += 256)                           \
            GLDS16(wsrc + i * 16, sm.st.wb + i * 16);                       \
    }

#define KX_PHASE(KX, xcur)                                                  \
    {                                                                       \
        f16x8 A[6];                                                         \
        _Pragma("unroll")                                                   \
        for (int rr = 0; rr < 6; ++rr) {                                    \
            int s = (wv * 4 + rr) * HLX + er + (KX);                        \
            A[rr] = *(const f16x8*)((xcur) + ((s * 64 + kg * 16) ^ ((s & 3) << 4))); \
        }                                                                   \
        _Pragma("unroll")                                                   \
        for (int ky = 0; ky < 3; ++ky) {                                    \
            const int tap = ky * 3 + (KX);                                  \
            f16x8 Bf[4];                                                    \
            _Pragma("unroll")                                               \
            for (int n = 0; n < 4; ++n) {                                   \
                int row = tap * 64 + n * 16 + er;                           \
                Bf[n] = *(const f16x8*)(sm.st.wb + ((row * 64 + kg * 16) ^ ((row & 3) << 4))); \
            }                                                               \
            _Pragma("unroll")                                               \
            for (int n = 0; n < 4; ++n)                                     \
                _Pragma("unroll")                                           \
                for (int m = 0; m < 4; ++m)                                 \
                    acc[m][n] = __builtin_amdgcn_mfma_f32_16x16x32_f16(A[m + ky], Bf[n], acc[m][n], 0, 0, 0); \
        }                                                                   \
    }

    // ---- prologue: stage chunk 0 ----
    X_ISSUE_H(0, 0, xr1)
    X_ISSUE_H(0, 3, xr2)
    W_STAGE(0)
    X_WRITE_H(sm.st.xs[0], 0, xr1)
    X_WRITE_H(sm.st.xs[0], 3, xr2)
    __syncthreads();

    #pragma unroll 1
    for (int c = 0; c < NCH; ++c) {
        char* xcur = sm.st.xs[c & 1];
        char* xalt = sm.st.xs[(c + 1) & 1];
        const bool more = (c < NCH - 1);

        if (more) { X_ISSUE_H(c + 1, 0, xr1) }      // 24 regs in flight
        __builtin_amdgcn_sched_barrier(0);          // pin issue position
        KX_PHASE(0, xcur)
        if (more) {
            X_WRITE_H(xalt, 0, xr1)                 // other buffer: no barrier needed
            X_ISSUE_H(c + 1, 3, xr2)
        }
        __builtin_amdgcn_sched_barrier(0);
        KX_PHASE(1, xcur)
        if (more) { X_WRITE_H(xalt, 3, xr2) }
        KX_PHASE(2, xcur)
        __syncthreads();                            // all reads of wb/xcur done
        if (more) { W_STAGE(c + 1) }                // only glds between barriers
        __syncthreads();                            // drains glds
    }

    // ---- epilogue: sigmoid+bias -> LDS scores [pixel][expert] ----
    #pragma unroll
    for (int m = 0; m < 4; ++m) {
        int pixbase = (wv * 4 + m) * 16 + kg * 4;   // C: row=(lane>>4)*4+reg, col=lane&15
        #pragma unroll
        for (int n = 0; n < 4; ++n) {
            int e = n * 16 + er;
            float bval = sbias[e];
            #pragma unroll
            for (int r = 0; r < 4; ++r)
                sm.scores[pixbase + r][e] =
                    __builtin_amdgcn_rcpf(1.f + __expf(-acc[m][n][r])) + bval;
        }
    }
    __syncthreads();

    // ---- per-pixel top-8: packed keys (score bits | 63-e), u32 max-tree ----
    {
        unsigned key[64];
        #pragma unroll
        for (int e = 0; e < 64; ++e)   // scores > 0 (sigmoid + zero bias) -> bit order = float order
            key[e] = (__float_as_uint(sm.scores[tid][e]) & ~63u) | (unsigned)(63 - e);

        float selv[TOPK]; int seli[TOPK];
        #pragma unroll
        for (int j = 0; j < TOPK; ++j) {
            unsigned t32[32];
            #pragma unroll
            for (int e = 0; e < 32; ++e) t32[e] = key[2*e] > key[2*e+1] ? key[2*e] : key[2*e+1];
            #pragma unroll
            for (int e = 0; e < 16; ++e) t32[e] = t32[2*e] > t32[2*e+1] ? t32[2*e] : t32[2*e+1];
            #pragma unroll
            for (int e = 0; e < 8; ++e)  t32[e] = t32[2*e] > t32[2*e+1] ? t32[2*e] : t32[2*e+1];
            #pragma unroll
            for (int e = 0; e < 4; ++e)  t32[e] = t32[2*e] > t32[2*e+1] ? t32[2*e] : t32[2*e+1];
            unsigned best = t32[0] > t32[1] ? t32[0] : t32[1];
            unsigned b2   = t32[2] > t32[3] ? t32[2] : t32[3];
            best = best > b2 ? best : b2;

            int e = 63 - (int)(best & 63u);
            seli[j] = e;
            selv[j] = __uint_as_float(best & ~63u) - sbias[e];
            #pragma unroll
            for (int e2 = 0; e2 < 64; ++e2) key[e2] = (key[e2] == best) ? 0u : key[e2];
        }
        float mx = selv[0];
        #pragma unroll
        for (int j = 1; j < TOPK; ++j) mx = fmaxf(mx, selv[j]);
        float ex[TOPK]; float ssum = 0.f;
        #pragma unroll
        for (int j = 0; j < TOPK; ++j) { ex[j] = __expf(selv[j] - mx); ssum += ex[j]; }
        const float inv = 1.f / ssum;

        const int pyg = by0 + (tid >> 4), pxg = bx0 + (tid & 15);
        #pragma unroll
        for (int j = 0; j < TOPK; ++j) {
            size_t o = ((size_t)(b * TOPK + j) * HH + pyg) * WW + pxg;
            out[W_OFF + o] = ex[j] * inv;
            out[I_OFF + o] = (float)seli[j];
            atomicAdd(&hist[seli[j]], 1);
        }
    }
    __syncthreads();
    if (tid < NE) atomicAdd(&gcount[tid], hist[tid]);
}

__global__ void finalize_kernel(const float* __restrict__ bias,
                                const float* __restrict__ history,
                                const int* __restrict__ gcount,
                                float* __restrict__ out)
{
    const int e = threadIdx.x;   // 64 threads = 1 wave
    float c = history[e] + (float)gcount[e];
    if (__all(c > 1e8f)) c = fmodf(c, 1e8f);
    float sum = c;
    #pragma unroll
    for (int off = 32; off > 0; off >>= 1) sum += __shfl_down(sum, off);
    float mean = __shfl(sum, 0) * (1.f / 64.f);
    float d = mean - c;
    float sg = (d > 0.f) ? 1.f : ((d < 0.f) ? -1.f : 0.f);
    out[C_OFF + e]  = c;
    out[NB_OFF + e] = bias[e] + 0.001f * sg;
}

extern "C" void kernel_launch(void* const* d_in, const int* in_sizes, int n_in,
                              void* d_out, int out_size, void* d_ws, size_t ws_size,
                              hipStream_t stream) {
    const float* x       = (const float*)d_in[0];
    const float* wg      = (const float*)d_in[1];
    const float* bias    = (const float*)d_in[2];
    const float* history = (const float*)d_in[3];
    float* out = (float*)d_out;

    char* wimg  = (char*)d_ws;
    int* gcount = (int*)((char*)d_ws + WIMG_BYTES);

    hipMemsetAsync(gcount, 0, NE * sizeof(int), stream);
    prep_w<<<(NCH * 9 * NE * 16 + 255) / 256, 256, 0, stream>>>(wg, wimg);
    conv_mfma_kernel<<<dim3(WW / TS, HH / TS, BB), 256, 0, stream>>>(x, wimg, bias, out, gcount);
    finalize_kernel<<<1, 64, 0, stream>>>(bias, history, gcount, out);
}